// Round 1
// baseline (1532.632 us; speedup 1.0000x reference)
//
#include <hip/hip_runtime.h>

#define N_IND 100000
#define N_COM 100000
#define N_TRU 100000
#define NTOT  300000
#define NEDGE 4800000
#define HDIM  64
#define SCAN_ELEMS 1024
#define NSCAN_BLOCKS 293   // ceil(300000/1024)

static __device__ __forceinline__ float elem4(const float4 v, int j) {
  return j == 0 ? v.x : j == 1 ? v.y : j == 2 ? v.z : v.w;
}

// ---------------- encoder: out[base+n] = x[n] @ W + b  (thread per node) ----------------
template <int K>
__global__ __launch_bounds__(256) void encode_kernel(
    const float* __restrict__ xin, const float* __restrict__ W,
    const float* __restrict__ b, float* __restrict__ xout, int n, int base) {
  int node = blockIdx.x * 256 + threadIdx.x;
  if (node >= n) return;
  float acc[HDIM];
#pragma unroll
  for (int f = 0; f < HDIM; ++f) acc[f] = b[f];  // uniform -> s_load
  const float4* xv = (const float4*)(xin + (size_t)node * K);
  for (int k4 = 0; k4 < K / 4; ++k4) {
    float4 xk = xv[k4];
#pragma unroll
    for (int j = 0; j < 4; ++j) {
      float xs = elem4(xk, j);
      int k = k4 * 4 + j;
#pragma unroll
      for (int f = 0; f < HDIM; ++f) acc[f] += xs * W[k * HDIM + f];  // uniform W -> s_load
    }
  }
  float4* ov = (float4*)(xout + (size_t)(base + node) * HDIM);
#pragma unroll
  for (int i = 0; i < HDIM / 4; ++i) {
    float4 o;
    o.x = acc[4 * i + 0]; o.y = acc[4 * i + 1]; o.z = acc[4 * i + 2]; o.w = acc[4 * i + 3];
    ov[i] = o;
  }
}

// ---------------- CSR build ----------------
__global__ __launch_bounds__(256) void count_kernel(const int* __restrict__ dst,
                                                    int* __restrict__ deg, int e) {
  int i = blockIdx.x * 256 + threadIdx.x;
  if (i < e) atomicAdd(&deg[dst[i]], 1);
}

__global__ __launch_bounds__(256) void scan_block_kernel(const int* __restrict__ deg,
                                                         int* __restrict__ off,
                                                         int* __restrict__ bsum, int n) {
  __shared__ int sv[256];
  int t = threadIdx.x;
  int base = blockIdx.x * SCAN_ELEMS + t * 4;
  int d0 = (base + 0 < n) ? deg[base + 0] : 0;
  int d1 = (base + 1 < n) ? deg[base + 1] : 0;
  int d2 = (base + 2 < n) ? deg[base + 2] : 0;
  int d3 = (base + 3 < n) ? deg[base + 3] : 0;
  int e0 = 0, e1 = d0, e2 = d0 + d1, e3 = d0 + d1 + d2;
  sv[t] = e3 + d3;
  __syncthreads();
  for (int o = 1; o < 256; o <<= 1) {
    int y = (t >= o) ? sv[t - o] : 0;
    __syncthreads();
    sv[t] += y;
    __syncthreads();
  }
  int pre = (t == 0) ? 0 : sv[t - 1];
  if (base + 0 < n) off[base + 0] = pre + e0;
  if (base + 1 < n) off[base + 1] = pre + e1;
  if (base + 2 < n) off[base + 2] = pre + e2;
  if (base + 3 < n) off[base + 3] = pre + e3;
  if (t == 255) bsum[blockIdx.x] = sv[255];
}

__global__ __launch_bounds__(512) void scan_bsums_kernel(int* __restrict__ bsum, int nb) {
  __shared__ int sv[512];
  int t = threadIdx.x;
  sv[t] = (t < nb) ? bsum[t] : 0;
  __syncthreads();
  for (int o = 1; o < 512; o <<= 1) {
    int y = (t >= o) ? sv[t - o] : 0;
    __syncthreads();
    sv[t] += y;
    __syncthreads();
  }
  if (t < nb) bsum[t] = (t == 0) ? 0 : sv[t - 1];
}

__global__ __launch_bounds__(256) void scan_add_kernel(int* __restrict__ off,
                                                       const int* __restrict__ bsum,
                                                       int* __restrict__ cursor, int n) {
  int i = blockIdx.x * 256 + threadIdx.x;
  if (i < n) {
    int o = off[i] + bsum[i >> 10];
    off[i] = o;
    cursor[i] = o;
  }
}

__global__ __launch_bounds__(256) void fill_kernel(const int* __restrict__ src,
                                                   const int* __restrict__ dst,
                                                   int* __restrict__ cursor,
                                                   int* __restrict__ eidx, int e) {
  int i = blockIdx.x * 256 + threadIdx.x;
  if (i < e) {
    int p = atomicAdd(&cursor[dst[i]], 1);
    eidx[p] = src[i];
  }
}

// ---------------- mean aggregation: 16 lanes per node, float4 per lane ----------------
__global__ __launch_bounds__(256) void aggregate_kernel(
    const float* __restrict__ x, const int* __restrict__ off, const int* __restrict__ deg,
    const int* __restrict__ eidx, float* __restrict__ mean, int n) {
  int tid = blockIdx.x * 256 + threadIdx.x;
  int node = tid >> 4;
  int lane = tid & 15;
  if (node >= n) return;
  int start = off[node];
  int d = deg[node];
  float4 acc = make_float4(0.f, 0.f, 0.f, 0.f);
  const float4* xv = (const float4*)x;
  for (int i = 0; i < d; ++i) {
    int s = eidx[start + i];
    float4 v = xv[(size_t)s * 16 + lane];
    acc.x += v.x; acc.y += v.y; acc.z += v.z; acc.w += v.w;
  }
  float inv = 1.0f / (float)(d > 0 ? d : 1);
  acc.x *= inv; acc.y *= inv; acc.z *= inv; acc.w *= inv;
  ((float4*)mean)[(size_t)node * 16 + lane] = acc;
}

// ---------------- combine: out = relu(mean@Wl + x@Wr + b)  (thread per node) ----------------
__global__ __launch_bounds__(256) void combine_kernel(
    const float* __restrict__ mean, const float* __restrict__ x,
    const float* __restrict__ Wl, const float* __restrict__ Wr,
    const float* __restrict__ bb, float* __restrict__ out, int n, int do_relu) {
  int node = blockIdx.x * 256 + threadIdx.x;
  if (node >= n) return;
  float acc[HDIM];
#pragma unroll
  for (int f = 0; f < HDIM; ++f) acc[f] = bb[f];
  const float4* mv = (const float4*)(mean + (size_t)node * HDIM);
  const float4* xv = (const float4*)(x + (size_t)node * HDIM);
  for (int k4 = 0; k4 < HDIM / 4; ++k4) {
    float4 mk = mv[k4];
    float4 xk = xv[k4];
#pragma unroll
    for (int j = 0; j < 4; ++j) {
      float ms = elem4(mk, j);
      float xs = elem4(xk, j);
      int k = k4 * 4 + j;
#pragma unroll
      for (int f = 0; f < HDIM; ++f)
        acc[f] += ms * Wl[k * HDIM + f] + xs * Wr[k * HDIM + f];  // uniform -> s_load
    }
  }
  float4* ov = (float4*)(out + (size_t)node * HDIM);
#pragma unroll
  for (int i = 0; i < HDIM / 4; ++i) {
    float4 o;
    o.x = acc[4 * i + 0]; o.y = acc[4 * i + 1]; o.z = acc[4 * i + 2]; o.w = acc[4 * i + 3];
    if (do_relu) {
      o.x = fmaxf(o.x, 0.f); o.y = fmaxf(o.y, 0.f);
      o.z = fmaxf(o.z, 0.f); o.w = fmaxf(o.w, 0.f);
    }
    ov[i] = o;
  }
}

// ---------------- classifier: out = relu(x@Wc1+bc1)@Wc2 + bc2 ----------------
__global__ __launch_bounds__(256) void classifier_kernel(
    const float* __restrict__ x, const float* __restrict__ W1, const float* __restrict__ b1,
    const float* __restrict__ W2, const float* __restrict__ b2,
    float* __restrict__ out, int n) {
  int node = blockIdx.x * 256 + threadIdx.x;
  if (node >= n) return;
  float h[32];
#pragma unroll
  for (int f = 0; f < 32; ++f) h[f] = b1[f];
  const float4* xv = (const float4*)(x + (size_t)node * HDIM);
  for (int k4 = 0; k4 < HDIM / 4; ++k4) {
    float4 xk = xv[k4];
#pragma unroll
    for (int j = 0; j < 4; ++j) {
      float xs = elem4(xk, j);
      int k = k4 * 4 + j;
#pragma unroll
      for (int f = 0; f < 32; ++f) h[f] += xs * W1[k * 32 + f];
    }
  }
  float o0 = b2[0], o1 = b2[1];
#pragma unroll
  for (int f = 0; f < 32; ++f) {
    float hv = fmaxf(h[f], 0.f);
    o0 += hv * W2[f * 2 + 0];
    o1 += hv * W2[f * 2 + 1];
  }
  float2 o;
  o.x = o0; o.y = o1;
  *(float2*)(out + (size_t)node * 2) = o;
}

extern "C" void kernel_launch(void* const* d_in, const int* in_sizes, int n_in,
                              void* d_out, int out_size, void* d_ws, size_t ws_size,
                              hipStream_t stream) {
  const float* x_ind = (const float*)d_in[0];
  const float* x_com = (const float*)d_in[1];
  const float* x_tru = (const float*)d_in[2];
  const int*   ei    = (const int*)d_in[3];
  const float* W_ind = (const float*)d_in[4];
  const float* b_ind = (const float*)d_in[5];
  const float* W_com = (const float*)d_in[6];
  const float* b_com = (const float*)d_in[7];
  const float* W_tru = (const float*)d_in[8];
  const float* b_tru = (const float*)d_in[9];
  const float* W1l = (const float*)d_in[10];
  const float* W1r = (const float*)d_in[11];
  const float* b1  = (const float*)d_in[12];
  const float* W2l = (const float*)d_in[13];
  const float* W2r = (const float*)d_in[14];
  const float* b2  = (const float*)d_in[15];
  const float* Wc1 = (const float*)d_in[16];
  const float* bc1 = (const float*)d_in[17];
  const float* Wc2 = (const float*)d_in[18];
  const float* bc2 = (const float*)d_in[19];

  const int* srcp = ei;           // edge_index[0]
  const int* dstp = ei + NEDGE;   // edge_index[1]

  // workspace layout
  size_t fcount = (size_t)NTOT * HDIM;  // 19.2M floats per buffer
  float* x0   = (float*)d_ws;
  float* x1   = x0 + fcount;
  float* mn   = x1 + fcount;
  int* eidx   = (int*)(mn + fcount);
  int* deg    = eidx + NEDGE;
  int* offp   = deg + NTOT;
  int* cursor = offp + NTOT;
  int* bsum   = cursor + NTOT;
  size_t needed = (3 * fcount + NEDGE + 3 * (size_t)NTOT + 1024) * 4;
  if (ws_size < needed) return;  // would corrupt; fail visibly instead

  hipMemsetAsync(deg, 0, (size_t)NTOT * sizeof(int), stream);

  // encoders
  encode_kernel<32><<<(N_IND + 255) / 256, 256, 0, stream>>>(x_ind, W_ind, b_ind, x0, N_IND, 0);
  encode_kernel<48><<<(N_COM + 255) / 256, 256, 0, stream>>>(x_com, W_com, b_com, x0, N_COM, N_IND);
  encode_kernel<24><<<(N_TRU + 255) / 256, 256, 0, stream>>>(x_tru, W_tru, b_tru, x0, N_TRU, N_IND + N_COM);

  // CSR build (by dst)
  count_kernel<<<(NEDGE + 255) / 256, 256, 0, stream>>>(dstp, deg, NEDGE);
  scan_block_kernel<<<NSCAN_BLOCKS, 256, 0, stream>>>(deg, offp, bsum, NTOT);
  scan_bsums_kernel<<<1, 512, 0, stream>>>(bsum, NSCAN_BLOCKS);
  scan_add_kernel<<<(NTOT + 255) / 256, 256, 0, stream>>>(offp, bsum, cursor, NTOT);
  fill_kernel<<<(NEDGE + 255) / 256, 256, 0, stream>>>(srcp, dstp, cursor, eidx, NEDGE);

  // SAGE layer 1
  aggregate_kernel<<<(NTOT * 16 + 255) / 256, 256, 0, stream>>>(x0, offp, deg, eidx, mn, NTOT);
  combine_kernel<<<(NTOT + 255) / 256, 256, 0, stream>>>(mn, x0, W1l, W1r, b1, x1, NTOT, 1);

  // SAGE layer 2
  aggregate_kernel<<<(NTOT * 16 + 255) / 256, 256, 0, stream>>>(x1, offp, deg, eidx, mn, NTOT);
  combine_kernel<<<(NTOT + 255) / 256, 256, 0, stream>>>(mn, x1, W2l, W2r, b2, x0, NTOT, 1);

  // classifier
  classifier_kernel<<<(NTOT + 255) / 256, 256, 0, stream>>>(x0, Wc1, bc1, Wc2, bc2,
                                                            (float*)d_out, NTOT);
}